// Round 7
// baseline (602.925 us; speedup 1.0000x reference)
//
#include <hip/hip_runtime.h>
#include <hip/hip_bf16.h>

typedef __bf16 bf16;
typedef __bf16 bf16x4 __attribute__((ext_vector_type(4)));
typedef __bf16 bf16x8 __attribute__((ext_vector_type(8)));
typedef float f32x4 __attribute__((ext_vector_type(4)));

#define B_ 2
#define H_ 32
#define HKV_ 8
#define S_ 2048
#define D_ 128
#define QT 64
#define KT 64
#define KST 136   // K LDS row stride (elems): 272B/row, 16B-aligned chunks
#define VST 68    // V^T LDS row stride: 136B/row (8B-aligned rows -> b64 reads)
#define PST 72    // P LDS row stride: 144B/row, 16B-aligned
#define NEG_BIG (-1.0e30f)
#define SCL 0.12751745f  // (1/sqrt(128)) * log2(e): softmax in exp2 domain

__device__ __forceinline__ bf16x8 cvt8(const float* f) {
  float4 a = *(const float4*)f;
  float4 b = *(const float4*)(f + 4);
  bf16x8 r = {(bf16)a.x, (bf16)a.y, (bf16)a.z, (bf16)a.w,
              (bf16)b.x, (bf16)b.y, (bf16)b.z, (bf16)b.w};
  return r;
}

// MFMA causal GQA flash attention. f32 inputs (bf16 compute), f32 OUTPUT.
// One block = 64 q-rows of one (b,h); wave w owns q-rows [w*16, w*16+16).
__global__ __launch_bounds__(256, 3) void fa_mfma(
    const float* __restrict__ q, const float* __restrict__ k,
    const float* __restrict__ v, float* __restrict__ out) {
  __shared__ bf16 Ks[KT * KST];      // K tile [key][d]
  __shared__ bf16 Vt[D_ * VST];      // V tile transposed [d][key]
  __shared__ bf16 Ps[4 * 16 * PST];  // per-wave P [qrow][key]

  const int tid = threadIdx.x, wave = tid >> 6, lane = tid & 63;
  const int col = lane & 15, quad = lane >> 4;
  const int bid = blockIdx.x;
  const int tq = 31 - (bid & 31);  // diagonal-heavy tiles first
  const int bh = bid >> 5, b = bh >> 5, h = bh & 31, hkv = h >> 2;  // GQA h/4

  const float* qh = q + (size_t)(b * H_ + h) * S_ * D_;
  const float* kh = k + (size_t)(b * HKV_ + hkv) * S_ * D_;
  const float* vh = v + (size_t)(b * HKV_ + hkv) * S_ * D_;
  float* oh = out + (size_t)(b * H_ + h) * S_ * D_;
  const int q0 = tq * QT;

  // Q A-fragments: A[m=lane&15][k=quad*8+j], chunk ks covers d in [ks*32,ks*32+32)
  bf16x8 qf[4];
  {
    const float* qrow = qh + (size_t)(q0 + wave * 16 + col) * D_ + quad * 8;
#pragma unroll
    for (int ks = 0; ks < 4; ++ks) qf[ks] = cvt8(qrow + ks * 32);
  }

  f32x4 o[8];
#pragma unroll
  for (int i = 0; i < 8; ++i) o[i] = (f32x4){0.f, 0.f, 0.f, 0.f};
  float m_i[4], l_i[4];
#pragma unroll
  for (int r = 0; r < 4; ++r) { m_i[r] = NEG_BIG; l_i[r] = 0.f; }

  for (int j = 0; j <= tq; ++j) {
    __syncthreads();  // prior iteration's LDS reads done before restage

    // ---- stage K tile [64][128]: f32 -> bf16, coalesced 32B/lane ----
#pragma unroll
    for (int i = 0; i < 4; ++i) {
      int c = tid + 256 * i, row = c >> 4, cc = c & 15;
      *(bf16x8*)&Ks[row * KST + cc * 8] =
          cvt8(kh + (size_t)(j * KT + row) * D_ + cc * 8);
    }
    // ---- stage V tile transposed [d][key] ----
    {
      int kb = (tid >> 4) * 4;     // 4 consecutive keys
      int dofs = (tid & 15) * 8;   // 8 consecutive d
      bf16x8 vv[4];
#pragma unroll
      for (int i = 0; i < 4; ++i)
        vv[i] = cvt8(vh + (size_t)(j * KT + kb + i) * D_ + dofs);
#pragma unroll
      for (int jj = 0; jj < 8; ++jj) {
        bf16x4 pk = {vv[0][jj], vv[1][jj], vv[2][jj], vv[3][jj]};
        *(bf16x4*)&Vt[(dofs + jj) * VST + kb] = pk;
      }
    }
    __syncthreads();

    // ---- S strip: 16 q-rows x 64 keys per wave ----
    float s[4][4];  // S[qrow=wave*16+quad*4+r][key=nt*16+col]
#pragma unroll
    for (int nt = 0; nt < 4; ++nt) {
      f32x4 acc = (f32x4){0.f, 0.f, 0.f, 0.f};
#pragma unroll
      for (int ks = 0; ks < 4; ++ks) {
        bf16x8 kf = *(const bf16x8*)&Ks[(nt * 16 + col) * KST + ks * 32 + quad * 8];
        acc = __builtin_amdgcn_mfma_f32_16x16x32_bf16(qf[ks], kf, acc, 0, 0, 0);
      }
#pragma unroll
      for (int r = 0; r < 4; ++r) s[nt][r] = acc[r] * SCL;
    }

    // causal mask on diagonal tile (key base == q base)
    if (j == tq) {
#pragma unroll
      for (int nt = 0; nt < 4; ++nt) {
        int kcol = nt * 16 + col;
#pragma unroll
        for (int r = 0; r < 4; ++r)
          if (kcol > wave * 16 + quad * 4 + r) s[nt][r] = NEG_BIG;
      }
    }

    // ---- online softmax (row's 16 lanes share quad: xor masks 1,2,4,8) ----
    float p[4][4];
#pragma unroll
    for (int r = 0; r < 4; ++r) {
      float mx = fmaxf(fmaxf(s[0][r], s[1][r]), fmaxf(s[2][r], s[3][r]));
#pragma unroll
      for (int off = 1; off < 16; off <<= 1)
        mx = fmaxf(mx, __shfl_xor(mx, off, 64));
      float mnew = fmaxf(m_i[r], mx);
      float alpha = exp2f(m_i[r] - mnew);
      float rs = 0.f;
#pragma unroll
      for (int nt = 0; nt < 4; ++nt) {
        float pv = exp2f(s[nt][r] - mnew);
        p[nt][r] = pv;
        rs += pv;
      }
#pragma unroll
      for (int off = 1; off < 16; off <<= 1)
        rs += __shfl_xor(rs, off, 64);
      l_i[r] = l_i[r] * alpha + rs;
      m_i[r] = mnew;
#pragma unroll
      for (int dt = 0; dt < 8; ++dt) o[dt][r] *= alpha;
    }

    // ---- P: C-layout -> A-layout via per-wave LDS round trip ----
    bf16* pw = &Ps[wave * 16 * PST];
#pragma unroll
    for (int nt = 0; nt < 4; ++nt)
#pragma unroll
      for (int r = 0; r < 4; ++r)
        pw[(quad * 4 + r) * PST + nt * 16 + col] = (bf16)p[nt][r];
    __syncthreads();  // conservative RAW cover (wave-local region)

    bf16x8 pf[2];
#pragma unroll
    for (int ks = 0; ks < 2; ++ks)
      pf[ks] = *(const bf16x8*)&pw[col * PST + ks * 32 + quad * 8];

    // ---- O += P·V ----
#pragma unroll
    for (int dt = 0; dt < 8; ++dt) {
#pragma unroll
      for (int ks = 0; ks < 2; ++ks) {
        const bf16* vb = &Vt[(dt * 16 + col) * VST + ks * 32 + quad * 8];
        bf16x4 lo = *(const bf16x4*)vb;       // VST=68: rows 8B-aligned -> 2x b64
        bf16x4 hi = *(const bf16x4*)(vb + 4);
        bf16x8 vf = {lo[0], lo[1], lo[2], lo[3], hi[0], hi[1], hi[2], hi[3]};
        o[dt] = __builtin_amdgcn_mfma_f32_16x16x32_bf16(pf[ks], vf, o[dt], 0, 0, 0);
      }
    }
  }

  // ---- epilogue: O / l, f32 output (the reference's output dtype) ----
#pragma unroll
  for (int r = 0; r < 4; ++r) {
    float inv = 1.f / l_i[r];
    float* orow = oh + (size_t)(q0 + wave * 16 + quad * 4 + r) * D_;
#pragma unroll
    for (int dt = 0; dt < 8; ++dt)
      orow[dt * 16 + col] = o[dt][r] * inv;
  }
}

extern "C" void kernel_launch(void* const* d_in, const int* in_sizes, int n_in,
                              void* d_out, int out_size, void* d_ws, size_t ws_size,
                              hipStream_t stream) {
  // Inputs in setup_inputs() dict order (q,k,v), confirmed by size probe in R6;
  // keep the size-based selection anyway (free, robust).
  const int QN = B_ * H_ * S_ * D_;
  int qi, ki, vi;
  if (in_sizes[0] == QN)      { qi = 0; ki = 1; vi = 2; }
  else if (in_sizes[1] == QN) { qi = 1; ki = 0; vi = 2; }
  else                        { qi = 2; ki = 0; vi = 1; }
  const float* q = (const float*)d_in[qi];
  const float* k = (const float*)d_in[ki];
  const float* v = (const float*)d_in[vi];
  float* out = (float*)d_out;
  fa_mfma<<<dim3(2048), dim3(256), 0, stream>>>(q, k, v, out);
}